// Round 2
// baseline (161.505 us; speedup 1.0000x reference)
//
#include <hip/hip_runtime.h>
#include <hip/hip_bf16.h>

#define KDIM 1024
#define NDIM 1024
#define NEXP 8
#define TTOK 8192
#define LDA  40   // round-1 fallback LDS stride

typedef __bf16 bf16x8 __attribute__((ext_vector_type(8)));
typedef __bf16 bf16x4 __attribute__((ext_vector_type(4)));
typedef float  f32x4  __attribute__((ext_vector_type(4)));

__device__ __forceinline__ void gl2lds16(const void* g, void* l) {
  __builtin_amdgcn_global_load_lds(
      (const __attribute__((address_space(1))) void*)g,
      (__attribute__((address_space(3))) void*)l, 16, 0, 0);
}

// ---------------- prepass: x fp32->bf16, W fp32 [K][N] -> Wt bf16 [N][K] ----------------
__global__ __launch_bounds__(256) void prepass(
    const float* __restrict__ x, const float* __restrict__ W,
    __bf16* __restrict__ xb, __bf16* __restrict__ Wt)
{
  __shared__ __align__(16) __bf16 Lt[64 * 72];   // [n][k], stride 72 (144B, 16B-aligned)
  const int t = threadIdx.x;
  if (blockIdx.x < 1024) {
    // x: 8M elems, 8 per thread per iter, 4 iters
    int gid = blockIdx.x * 256 + t;
#pragma unroll
    for (int p = 0; p < 4; ++p) {
      size_t i8 = (size_t)(gid + p * 262144) * 8;
      float4 a = *(const float4*)(x + i8);
      float4 b = *(const float4*)(x + i8 + 4);
      bf16x8 v;
      v[0] = (__bf16)a.x; v[1] = (__bf16)a.y; v[2] = (__bf16)a.z; v[3] = (__bf16)a.w;
      v[4] = (__bf16)b.x; v[5] = (__bf16)b.y; v[6] = (__bf16)b.z; v[7] = (__bf16)b.w;
      *(bf16x8*)(xb + i8) = v;
    }
  } else {
    // W transpose: 64x64 tile per block, 8 experts x 16 x 16 tiles
    int bid = blockIdx.x - 1024;
    int e = bid >> 8, r = bid & 255;
    int k0 = (r >> 4) * 64, n0 = (r & 15) * 64;
    const float* Wp = W + (size_t)e * KDIM * NDIM;
    int rr0 = t >> 4, c4 = t & 15;
#pragma unroll
    for (int p = 0; p < 4; ++p) {
      int kk = rr0 + p * 16;
      float4 v = *(const float4*)(Wp + (size_t)(k0 + kk) * NDIM + n0 + c4 * 4);
      Lt[(c4 * 4 + 0) * 72 + kk] = (__bf16)v.x;
      Lt[(c4 * 4 + 1) * 72 + kk] = (__bf16)v.y;
      Lt[(c4 * 4 + 2) * 72 + kk] = (__bf16)v.z;
      Lt[(c4 * 4 + 3) * 72 + kk] = (__bf16)v.w;
    }
    __syncthreads();
    __bf16* Wte = Wt + (size_t)e * NDIM * KDIM;
    int n = t >> 2, kq = t & 3;
#pragma unroll
    for (int q = 0; q < 2; ++q) {
      int kqq = kq + q * 4;
      bf16x8 v = *(const bf16x8*)(Lt + n * 72 + kqq * 8);
      *(bf16x8*)(Wte + (size_t)(n0 + n) * KDIM + k0 + kqq * 8) = v;
    }
  }
}

// ---------------- main GEMM: bf16 inputs, global_load_lds staging, m97 structure ----------------
__global__ __launch_bounds__(256) void moe_gemm_bf16(
    const __bf16* __restrict__ xb, const __bf16* __restrict__ Wt,
    const int* __restrict__ gs, const float* __restrict__ bias,
    float* __restrict__ out)
{
  // LDS layout: slot s (16B) = [kh = s>>7][row = s&127] -> elems kh*1024 + row*8
  __shared__ __align__(16) __bf16 Al[4096];  // 8 KiB
  __shared__ __align__(16) __bf16 Bl[4096];  // 8 KiB

  // decode flat m-tile id -> (expert, row0, rows)
  int y = blockIdx.y;
  int e = 0, row0 = 0, rows = 0, found = 0, off = 0;
#pragma unroll
  for (int i = 0; i < NEXP; ++i) {
    int g = gs[i];
    int tc = (g + 127) >> 7;
    if (!found) {
      if (y < tc) { found = 1; e = i; row0 = off + y * 128; rows = min(128, g - y * 128); }
      else y -= tc;
    }
    off += g;
  }
  if (!found) return;
  const int n0 = blockIdx.x * 128;

  const int t = threadIdx.x, lane = t & 63, wv = t >> 6;
  const int wm = wv & 1, wn = wv >> 1, lm = lane & 15, lg = lane >> 4;

  // staging: wave wv issues chunks c0,c1 (64 slots x 16B = 1 KiB each) for A and B
  const int c0 = wv * 2, c1 = wv * 2 + 1;
  const int s0 = c0 * 64 + lane, s1 = c1 * 64 + lane;
  const int r0 = s0 & 127, k0h = s0 >> 7;
  const int r1 = s1 & 127, k1h = s1 >> 7;

  // rows >= `rows` read in-ws garbage (finite bf16); their outputs are never stored
  const __bf16* gA0 = xb + (size_t)(row0 + r0) * KDIM + k0h * 8;
  const __bf16* gA1 = xb + (size_t)(row0 + r1) * KDIM + k1h * 8;
  const __bf16* Wte = Wt + (size_t)e * NDIM * KDIM;
  const __bf16* gB0 = Wte + (size_t)(n0 + r0) * KDIM + k0h * 8;
  const __bf16* gB1 = Wte + (size_t)(n0 + r1) * KDIM + k1h * 8;
  __bf16* lA0 = Al + c0 * 512;  // wave-uniform LDS bases
  __bf16* lA1 = Al + c1 * 512;
  __bf16* lB0 = Bl + c0 * 512;
  __bf16* lB1 = Bl + c1 * 512;

  f32x4 acc[4][4] = {};

#pragma unroll 1
  for (int kt = 0; kt < KDIM / 32; ++kt) {
    const int ko = kt * 32;
    gl2lds16(gA0 + ko, lA0);
    gl2lds16(gA1 + ko, lA1);
    gl2lds16(gB0 + ko, lB0);
    gl2lds16(gB1 + ko, lB1);
    __syncthreads();           // compiler drains vmcnt(0) before s_barrier

    bf16x8 af[4], bfr[4];
#pragma unroll
    for (int i = 0; i < 4; ++i)
      af[i] = *(const bf16x8*)(Al + lg * 1024 + (wm * 64 + i * 16 + lm) * 8);
#pragma unroll
    for (int j = 0; j < 4; ++j)
      bfr[j] = *(const bf16x8*)(Bl + lg * 1024 + (wn * 64 + j * 16 + lm) * 8);

#pragma unroll
    for (int i = 0; i < 4; ++i)
#pragma unroll
      for (int j = 0; j < 4; ++j)
        acc[i][j] = __builtin_amdgcn_mfma_f32_16x16x32_bf16(af[i], bfr[j], acc[i][j], 0, 0, 0);
    __syncthreads();
  }

  float bj[4];
#pragma unroll
  for (int j = 0; j < 4; ++j) bj[j] = bias[e * NDIM + n0 + wn * 64 + j * 16 + lm];
  float* op = out + (size_t)row0 * NDIM + n0;
#pragma unroll
  for (int i = 0; i < 4; ++i)
#pragma unroll
    for (int r = 0; r < 4; ++r) {
      int rr = wm * 64 + i * 16 + lg * 4 + r;   // C/D: row = quad*4 + reg, col = lane&15
      if (rr < rows) {
#pragma unroll
        for (int j = 0; j < 4; ++j)
          op[(size_t)rr * NDIM + wn * 64 + j * 16 + lm] = acc[i][j][r] + bj[j];
      }
    }
}

// ---------------- round-1 fallback (fp32 in-loop conversion) for small ws ----------------
__global__ __launch_bounds__(256) void moe_gemm_kernel(
    const float* __restrict__ x, const int* __restrict__ gs,
    const float* __restrict__ W, const float* __restrict__ bias,
    float* __restrict__ out)
{
  __shared__ __bf16 Al[128 * LDA];
  __shared__ __bf16 Bl[128 * LDA];
  const int e = blockIdx.z, mt = blockIdx.y, nt = blockIdx.x;
  int off = 0;
#pragma unroll
  for (int i = 0; i < NEXP; ++i) { int g = gs[i]; if (i < e) off += g; }
  const int ge = gs[e];
  const int m0 = mt * 128;
  if (m0 >= ge) return;
  const int rows = min(128, ge - m0);
  const int row0 = off + m0;
  const int n0 = nt * 128;
  const int t = threadIdx.x, lane = t & 63, wv = t >> 6;
  const int wm = wv & 1, wn = wv >> 1, lm = lane & 15, lg = lane >> 4;
  const int am = t >> 3, kq = t & 7, nb = t & 127, kh = t >> 7;
  float4 aReg[4]; float bReg[16];
  const float* Wp = W + (size_t)e * KDIM * NDIM + n0 + nb;
  auto load_tile = [&](int kt) {
#pragma unroll
    for (int p = 0; p < 4; ++p) {
      int r = am + 32 * p;
      if (r < rows) aReg[p] = *(const float4*)(x + (size_t)(row0 + r) * KDIM + kt * 32 + kq * 4);
      else aReg[p] = make_float4(0.f, 0.f, 0.f, 0.f);
    }
    const float* wp = Wp + (size_t)(kt * 32 + kh * 16) * NDIM;
#pragma unroll
    for (int j = 0; j < 16; ++j) bReg[j] = wp[(size_t)j * NDIM];
  };
  auto store_tile = [&]() {
#pragma unroll
    for (int p = 0; p < 4; ++p) {
      bf16x4 v;
      v[0] = (__bf16)aReg[p].x; v[1] = (__bf16)aReg[p].y;
      v[2] = (__bf16)aReg[p].z; v[3] = (__bf16)aReg[p].w;
      *(bf16x4*)(Al + (am + 32 * p) * LDA + kq * 4) = v;
    }
    bf16x8 b0, b1;
#pragma unroll
    for (int j = 0; j < 8; ++j) { b0[j] = (__bf16)bReg[j]; b1[j] = (__bf16)bReg[8 + j]; }
    *(bf16x8*)(Bl + nb * LDA + kh * 16) = b0;
    *(bf16x8*)(Bl + nb * LDA + kh * 16 + 8) = b1;
  };
  f32x4 acc[4][4] = {};
  load_tile(0);
#pragma unroll 1
  for (int kt = 0; kt < KDIM / 32; ++kt) {
    __syncthreads();
    store_tile();
    __syncthreads();
    if (kt + 1 < KDIM / 32) load_tile(kt + 1);
    bf16x8 af[4], bfr[4];
#pragma unroll
    for (int i = 0; i < 4; ++i)
      af[i] = *(const bf16x8*)(Al + (wm * 64 + i * 16 + lm) * LDA + lg * 8);
#pragma unroll
    for (int j = 0; j < 4; ++j)
      bfr[j] = *(const bf16x8*)(Bl + (wn * 64 + j * 16 + lm) * LDA + lg * 8);
#pragma unroll
    for (int i = 0; i < 4; ++i)
#pragma unroll
      for (int j = 0; j < 4; ++j)
        acc[i][j] = __builtin_amdgcn_mfma_f32_16x16x32_bf16(af[i], bfr[j], acc[i][j], 0, 0, 0);
  }
  float bj[4];
#pragma unroll
  for (int j = 0; j < 4; ++j) bj[j] = bias[e * NDIM + n0 + wn * 64 + j * 16 + lm];
  float* op = out + (size_t)row0 * NDIM + n0;
#pragma unroll
  for (int i = 0; i < 4; ++i)
#pragma unroll
    for (int r = 0; r < 4; ++r) {
      int rr = wm * 64 + i * 16 + lg * 4 + r;
      if (rr < rows) {
#pragma unroll
        for (int j = 0; j < 4; ++j)
          op[(size_t)rr * NDIM + wn * 64 + j * 16 + lm] = acc[i][j][r] + bj[j];
      }
    }
}

extern "C" void kernel_launch(void* const* d_in, const int* in_sizes, int n_in,
                              void* d_out, int out_size, void* d_ws, size_t ws_size,
                              hipStream_t stream) {
  const float* x    = (const float*)d_in[0];
  const int*   gs   = (const int*)d_in[1];
  const float* W    = (const float*)d_in[2];
  const float* bias = (const float*)d_in[3];
  float*       out  = (float*)d_out;

  const size_t xb_bytes = (size_t)TTOK * KDIM * 2;
  const size_t wt_bytes = (size_t)NEXP * KDIM * NDIM * 2;
  if (ws_size >= xb_bytes + wt_bytes) {
    __bf16* xb = (__bf16*)d_ws;
    __bf16* Wt = (__bf16*)((char*)d_ws + xb_bytes);
    prepass<<<dim3(1024 + 2048), 256, 0, stream>>>(x, W, xb, Wt);
    // grid: 8 n-tiles x (sum over experts of ceil(g_e/128) <= 72) m-tiles
    moe_gemm_bf16<<<dim3(NDIM / 128, 72), 256, 0, stream>>>(xb, Wt, gs, bias, out);
  } else {
    moe_gemm_kernel<<<dim3(NDIM / 128, TTOK / 128, NEXP), 256, 0, stream>>>(x, gs, W, bias, out);
  }
}